// Round 8
// baseline (295.566 us; speedup 1.0000x reference)
//
#include <hip/hip_runtime.h>
#include <math.h>

// TaskAdaptiveRouter: logits = x @ Wr[:, :2048]^T + task_logits; softmax; top2; aux.
// B=4, L=4096 -> 16384 tokens; D=2048; DT=16; E=64; K=2; TEMP=1.
//
// d_out (f32): [0,32768) topw ; [32768,65536) topi(float) ; [65536,1114112) probs ;
//              [1114112] aux.
// d_ws  (f32): [0,256) task logits tl[4][64] ; [256,1280) P/F slots [8][{P:64,F:64}].
//
// k2: grid 256 x 512thr (8 waves). Wave wv: 64 tokens (lane=token) x 8 experts.
// Key ratio: per 4-k subtile each wave does 1 ds_read_b128 (x) + 32 FMAs -> 32
// FMA-instr per b128 >= 24 needed to clear the ~12cy/CU b128 throughput wall.
// W: plain C f32x4 loads from a readfirstlane-uniform pointer -> compiler emits
// s_load_dwordx4 and owns all SMEM scheduling (no hand-rolled waits; R3/R5/R6
// post-mortems: every manual W pipeline tripped a compiler-model hazard).
// x: global_load_lds, 1 DMA per wave per tile, triple-buffer, counted vmcnt(1),
// fenced barriers (R6's BAR).

#define DDIM 2048
#define WROW 2064          // W_router row stride (floats)

typedef unsigned int u32;
typedef const __attribute__((address_space(1))) u32* gp1;
typedef __attribute__((address_space(3))) u32* lp3;
using f32x4 = __attribute__((ext_vector_type(4))) float;

// barrier with compiler-level memory fence + scheduler pin (no extra runtime cost)
#define BAR() do {                                                              \
        __builtin_amdgcn_s_barrier();                                           \
        asm volatile("" ::: "memory");                                          \
        __builtin_amdgcn_sched_barrier(0);                                      \
    } while (0)

// ---------------- kernel 1: task proj + task logits + zero P/F slots -------------
__global__ void k1_task(const float* __restrict__ z, const float* __restrict__ Wp,
                        const float* __restrict__ bp, const float* __restrict__ Wr,
                        const float* __restrict__ eb, float* __restrict__ wsb) {
    __shared__ float tp[4][16];
    const int t = threadIdx.x;
    if (t < 64) {
        const int b = t >> 4, r = t & 15;
        float s = bp[r];
        #pragma unroll
        for (int i = 0; i < 16; ++i) s += z[b * 16 + i] * Wp[r * 16 + i];
        tp[b][r] = 0.5f * s * (1.0f + erff(s * 0.70710678118654752440f));
    }
    #pragma unroll
    for (int i = t; i < 1024; i += 256) wsb[256 + i] = 0.0f;   // zero 8 P/F slots
    __syncthreads();
    {
        const int b = t >> 6, e = t & 63;
        const float* wr = Wr + (size_t)e * WROW + DDIM;
        float s = eb[e];
        #pragma unroll
        for (int i = 0; i < 16; ++i) s += tp[b][i] * wr[i];
        wsb[b * 64 + e] = s;
    }
}

// ---------------- kernel 2: fused logits + softmax + top2 + probs + P/f ----------
__global__ __launch_bounds__(512, 1) void k2_fused(const float* __restrict__ x,
                                                   const float* __restrict__ Wr,
                                                   const float* __restrict__ wsb,
                                                   float* __restrict__ wacc,
                                                   float* __restrict__ out) {
    __shared__ __align__(16) float xbuf[3 * 2048];   // triple-buffered x tiles (24 KB)
    __shared__ __align__(16) float lg[64 * 68];      // logit exchange (17 KB)
    __shared__ __align__(16) float pf[8 * 128];      // P/f partials (4 KB)

    const int tid  = threadIdx.x;
    const int wv   = __builtin_amdgcn_readfirstlane(tid >> 6);  // uniform wave id
    const int lane = tid & 63;
    const int tok0 = blockIdx.x * 64;
    const int bb   = tok0 >> 12;            // batch index (uniform)
    const int e0   = wv * 8;                // uniform

    // x DMA source: wave wv stages subtile-chunk wv of each tile (16 B/lane)
    const float* xsrc = x + (size_t)(tok0 + lane) * DDIM + wv * 4;
    // uniform W base for this wave's 8 experts -> compiler proves SMEM-able
    const float* wb = Wr + (size_t)e0 * WROW;

    float acc[8];
    #pragma unroll
    for (int e = 0; e < 8; ++e) acc[e] = wsb[bb * 64 + e0 + e];  // task logits

#define STAGE(t) __builtin_amdgcn_global_load_lds(                              \
        (gp1)(xsrc + (t) * 32),                                                 \
        (lp3)(&xbuf[((t) % 3) * 2048 + wv * 256]), 16, 0, 0)

#define COMPUTE(t) do {                                                         \
        const float* bufc = &xbuf[((t) % 3) * 2048];                            \
        const float* wt   = wb + (t) * 32;                                      \
        _Pragma("unroll")                                                       \
        for (int q = 0; q < 8; ++q) {                                           \
            const float4 xv = *(const float4*)(bufc + q * 256 + (lane << 2));   \
            _Pragma("unroll")                                                   \
            for (int e = 0; e < 8; ++e) {                                       \
                const f32x4 wq = *(const f32x4*)(wt + (size_t)e * WROW + 4 * q);\
                acc[e] += xv.x * wq.x; acc[e] += xv.y * wq.y;                   \
                acc[e] += xv.z * wq.z; acc[e] += xv.w * wq.w;                   \
            }                                                                   \
        }                                                                       \
    } while (0)

    STAGE(0); STAGE(1);
    for (int t = 0; t < 62; ++t) {
        asm volatile("s_waitcnt vmcnt(1)" ::: "memory");   // my tile-t chunk landed
        asm volatile("s_waitcnt lgkmcnt(0)" ::: "memory"); // my t-1 ds_reads done
        BAR();                                             // tile t ready for all
        STAGE(t + 2);                                      // overwrite slot (t-1)%3
        COMPUTE(t);
    }
    asm volatile("s_waitcnt vmcnt(1)" ::: "memory");
    asm volatile("s_waitcnt lgkmcnt(0)" ::: "memory");
    BAR();
    COMPUTE(62);
    asm volatile("s_waitcnt vmcnt(0)" ::: "memory");
    asm volatile("s_waitcnt lgkmcnt(0)" ::: "memory");
    BAR();
    COMPUTE(63);
#undef STAGE
#undef COMPUTE

    // ---- logit exchange: lane=token writes its 8 experts ----
    #pragma unroll
    for (int e = 0; e < 8; e += 4) {
        float4 v;
        v.x = acc[e]; v.y = acc[e + 1]; v.z = acc[e + 2]; v.w = acc[e + 3];
        *(float4*)&lg[lane * 68 + e0 + e] = v;
    }
    __syncthreads();

    // ---- softmax/top2 for tokens 8wv..8wv+7 ; lane = expert ----
    {
        float pacc = 0.0f, facc = 0.0f;
        for (int i = 0; i < 8; ++i) {
            const int tk = wv * 8 + i;
            const float v = lg[tk * 68 + lane];
            float m1 = v; int i1 = lane;
            #pragma unroll
            for (int off = 32; off; off >>= 1) {
                const float ov = __shfl_xor(m1, off, 64);
                const int   oi = __shfl_xor(i1, off, 64);
                if (ov > m1 || (ov == m1 && oi < i1)) { m1 = ov; i1 = oi; }
            }
            const float vx = (lane == i1) ? -3.4e38f : v;
            float m2 = vx; int i2 = lane;
            #pragma unroll
            for (int off = 32; off; off >>= 1) {
                const float ov = __shfl_xor(m2, off, 64);
                const int   oi = __shfl_xor(i2, off, 64);
                if (ov > m2 || (ov == m2 && oi < i2)) { m2 = ov; i2 = oi; }
            }
            const float p = __expf(v - m1);
            float s = p;
            #pragma unroll
            for (int off = 32; off; off >>= 1) s += __shfl_xor(s, off, 64);
            const float rZ = 1.0f / s;
            const float pn = p * rZ;
            const int   T  = tok0 + tk;
            out[65536 + (size_t)T * 64 + lane] = pn;      // coalesced 256 B
            pacc += pn;
            facc += (lane == i1 ? 1.0f : 0.0f) + (lane == i2 ? 1.0f : 0.0f);
            if (lane == 0) {
                const float q1 = rZ, q2 = __expf(m2 - m1) * rZ;
                const float dn = 1.0f / (q1 + q2 + 1e-8f);
                float2 tw; tw.x = q1 * dn; tw.y = q2 * dn;
                *(float2*)(out + (size_t)T * 2) = tw;
                float2 ti; ti.x = (float)i1; ti.y = (float)i2;
                *(float2*)(out + 32768 + (size_t)T * 2) = ti;
            }
        }
        pf[wv * 128 + lane]      = pacc;
        pf[wv * 128 + 64 + lane] = facc;
    }
    __syncthreads();

    // ---- block-level P/f reduce -> one atomic per address per block (8 slots) ----
    if (wv == 0) {
        float ps = 0.0f, fs = 0.0f;
        #pragma unroll
        for (int w2 = 0; w2 < 8; ++w2) {
            ps += pf[w2 * 128 + lane];
            fs += pf[w2 * 128 + 64 + lane];
        }
        const int slot = blockIdx.x & 7;
        atomicAdd(wacc + slot * 128 + lane, ps);
        atomicAdd(wacc + slot * 128 + 64 + lane, fs);
    }
}

// ---------------- kernel 3: aux loss ----------------------------------------------
__global__ void k3_aux(const float* __restrict__ wsb, float* __restrict__ out) {
    const int e = threadIdx.x;  // 64 threads
    float P = 0.0f, F = 0.0f;
    #pragma unroll
    for (int s = 0; s < 8; ++s) {
        P += wsb[256 + s * 128 + e];
        F += wsb[256 + s * 128 + 64 + e];
    }
    float val = P * F;
    #pragma unroll
    for (int off = 32; off; off >>= 1) val += __shfl_xor(val, off, 64);
    if (e == 0)
        out[1114112] = 64.0f * val / (16384.0f * 2.0f * 16384.0f);
}

extern "C" void kernel_launch(void* const* d_in, const int* in_sizes, int n_in,
                              void* d_out, int out_size, void* d_ws, size_t ws_size,
                              hipStream_t stream) {
    (void)in_sizes; (void)n_in; (void)out_size; (void)ws_size;
    const float* x  = (const float*)d_in[0];
    const float* z  = (const float*)d_in[1];
    const float* Wr = (const float*)d_in[2];
    const float* Wp = (const float*)d_in[3];
    const float* bp = (const float*)d_in[4];
    const float* eb = (const float*)d_in[5];
    float* out = (float*)d_out;
    float* wsb = (float*)d_ws;

    hipLaunchKernelGGL(k1_task,  dim3(1),   dim3(256), 0, stream, z, Wp, bp, Wr, eb, wsb);
    hipLaunchKernelGGL(k2_fused, dim3(256), dim3(512), 0, stream, x, Wr, wsb, wsb + 256, out);
    hipLaunchKernelGGL(k3_aux,   dim3(1),   dim3(64),  0, stream, wsb, out);
}

// Round 9
// 66.916 us; speedup vs baseline: 4.4170x; 4.4170x over previous
//
#include <hip/hip_runtime.h>
#include <math.h>

// TaskAdaptiveRouter via split-bf16 4-pass MFMA.
// logits = x @ Wr[:, :2048]^T + task_logits; softmax; top2; aux.
// x = xh + xl (bf16 RNE two-term split), W = wh + wl; 4 MFMA passes (hh,hl,lh,ll)
// recover ~f32 precision (err ~2^-18 rel << f32 sum-order noise). f32 VALU FMA is
// dead (R1-R7: LDS-throughput / lgkm-vmcnt counter hazards cap it at ~94us);
// MFMA at 4x FLOPs = 7us compute -> HBM-bound ~21us.
//
// d_out (f32): [0,32768) topw ; [32768,65536) topi(float) ; [65536,1114112) probs ;
//              [1114112] aux.
// d_ws: [0,256) tl[4][64] ; [256,1280) P/F slots ; floats [1280..) = W-frags:
//       whF 65536 u32 (256KB) then wlF 65536 u32. B-frag layout: dword index
//       ((step*4+grp)*64 + lane)*4 + d ; short8 elem j <-> k = step*32+(lane>>4)*8+j,
//       expert e = grp*16 + (lane&15).

#define DDIM 2048
#define WROW 2064

typedef unsigned int u32;
typedef unsigned short u16;
using short8 = __attribute__((ext_vector_type(8))) short;
using f32x4  = __attribute__((ext_vector_type(4))) float;

__device__ __forceinline__ u16 bf16rne(float f) {
    u32 u = __float_as_uint(f);
    return (u16)((u + 0x7FFFu + ((u >> 16) & 1u)) >> 16);
}

// ---------------- kernel 0: build W B-fragments (hi/lo bf16) ----------------------
__global__ void k0_wsplit(const float* __restrict__ Wr, u32* __restrict__ wh,
                          u32* __restrict__ wl) {
    const int g = blockIdx.x * 256 + threadIdx.x;    // 0..65535
    const int e  = g >> 10;                          // expert 0..63
    const int kp = g & 1023;                         // k-pair 0..1023
    const int k  = kp * 2;
    const int step = k >> 5, kb = (k >> 3) & 3, d = (k >> 1) & 3;
    const int grp = e >> 4, lane = kb * 16 + (e & 15);
    const float w0 = Wr[(size_t)e * WROW + k];
    const float w1 = Wr[(size_t)e * WROW + k + 1];
    const u16 h0 = bf16rne(w0);
    const u16 h1 = bf16rne(w1);
    const u16 l0 = bf16rne(w0 - __uint_as_float((u32)h0 << 16));
    const u16 l1 = bf16rne(w1 - __uint_as_float((u32)h1 << 16));
    const u32 oi = (u32)(((step * 4 + grp) * 64 + lane) * 4 + d);
    wh[oi] = ((u32)h1 << 16) | h0;
    wl[oi] = ((u32)l1 << 16) | l0;
}

// ---------------- kernel 1: task proj + task logits + zero P/F slots -------------
__global__ void k1_task(const float* __restrict__ z, const float* __restrict__ Wp,
                        const float* __restrict__ bp, const float* __restrict__ Wr,
                        const float* __restrict__ eb, float* __restrict__ wsb) {
    __shared__ float tp[4][16];
    const int t = threadIdx.x;
    if (t < 64) {
        const int b = t >> 4, r = t & 15;
        float s = bp[r];
        #pragma unroll
        for (int i = 0; i < 16; ++i) s += z[b * 16 + i] * Wp[r * 16 + i];
        tp[b][r] = 0.5f * s * (1.0f + erff(s * 0.70710678118654752440f));
    }
    #pragma unroll
    for (int i = t; i < 1024; i += 256) wsb[256 + i] = 0.0f;   // zero 8 P/F slots
    __syncthreads();
    {
        const int b = t >> 6, e = t & 63;
        const float* wr = Wr + (size_t)e * WROW + DDIM;
        float s = eb[e];
        #pragma unroll
        for (int i = 0; i < 16; ++i) s += tp[b][i] * wr[i];
        wsb[b * 64 + e] = s;
    }
}

// ---------------- kernel 2: MFMA logits + softmax + top2 + probs + P/f -----------
__global__ __launch_bounds__(256) void k2_mfma(const float* __restrict__ x,
                                               const float* __restrict__ wsb,
                                               const short8* __restrict__ bfh,
                                               const short8* __restrict__ bfl,
                                               float* __restrict__ wacc,
                                               float* __restrict__ out) {
    __shared__ float lg[64 * 68];    // logit exchange (17 KB)
    __shared__ float pf[4 * 128];    // P/f partials (2 KB)

    const int tid   = threadIdx.x;
    const int wv    = tid >> 6;      // wave 0..3
    const int lane  = tid & 63;
    const int row   = lane & 15;     // A row (token within wave tile)
    const int kg    = lane >> 4;     // k-group 0..3
    const int tok0b = blockIdx.x * 64;
    const int tok0  = tok0b + wv * 16;
    const int bb    = tok0b >> 12;   // batch (uniform per block)

    const float* xp = x + (size_t)(tok0 + row) * DDIM + kg * 8;

    f32x4 acc[4];
    #pragma unroll
    for (int g = 0; g < 4; ++g) {
        const float tl = wsb[bb * 64 + g * 16 + row];  // task logits + bias
        acc[g] = (f32x4){tl, tl, tl, tl};
    }

#define LOADB(s, BH, BL) do {                                                   \
        _Pragma("unroll")                                                       \
        for (int g = 0; g < 4; ++g) {                                           \
            BH[g] = bfh[((s) * 4 + g) * 64 + lane];                             \
            BL[g] = bfl[((s) * 4 + g) * 64 + lane];                             \
        }                                                                       \
    } while (0)

#define MSTEP(xa, xb, BH, BL) do {                                              \
        const float vv[8] = {xa.x, xa.y, xa.z, xa.w, xb.x, xb.y, xb.z, xb.w};   \
        short8 Ah, Al;                                                          \
        _Pragma("unroll")                                                       \
        for (int j = 0; j < 8; ++j) {                                           \
            const float v = vv[j];                                              \
            const u16 h = bf16rne(v);                                           \
            const u16 l = bf16rne(v - __uint_as_float((u32)h << 16));           \
            Ah[j] = (short)h; Al[j] = (short)l;                                 \
        }                                                                       \
        _Pragma("unroll")                                                       \
        for (int g = 0; g < 4; ++g) {                                           \
            acc[g] = __builtin_amdgcn_mfma_f32_16x16x32_bf16(Ah, BH[g], acc[g], 0, 0, 0); \
            acc[g] = __builtin_amdgcn_mfma_f32_16x16x32_bf16(Ah, BL[g], acc[g], 0, 0, 0); \
            acc[g] = __builtin_amdgcn_mfma_f32_16x16x32_bf16(Al, BH[g], acc[g], 0, 0, 0); \
            acc[g] = __builtin_amdgcn_mfma_f32_16x16x32_bf16(Al, BL[g], acc[g], 0, 0, 0); \
        }                                                                       \
    } while (0)

    // software pipeline: x depth-2 (HBM), B depth-1 (L2); tails clamp in-bounds
    float4 xA0 = *(const float4*)(xp);
    float4 xB0 = *(const float4*)(xp + 4);
    float4 xA1 = *(const float4*)(xp + 32);
    float4 xB1 = *(const float4*)(xp + 36);
    short8 bh0[4], bl0[4], bh1[4], bl1[4];
    LOADB(0, bh0, bl0);

    for (int t = 0; t < 64; t += 2) {
        // even half: consume x(t), B(t); prefetch x(t+2), B(t+1)
        const float* xq = xp + ((t + 2 < 64) ? (t + 2) * 32 : 0);
        const float4 pA = *(const float4*)(xq);
        const float4 pB = *(const float4*)(xq + 4);
        LOADB(t + 1, bh1, bl1);
        MSTEP(xA0, xB0, bh0, bl0);
        xA0 = pA; xB0 = pB;
        // odd half: consume x(t+1), B(t+1); prefetch x(t+3), B(t+2)
        const float* xr = xp + ((t + 3 < 64) ? (t + 3) * 32 : 0);
        const float4 qA = *(const float4*)(xr);
        const float4 qB = *(const float4*)(xr + 4);
        const int s2 = (t + 2 < 64) ? t + 2 : 0;
        LOADB(s2, bh0, bl0);
        MSTEP(xA1, xB1, bh1, bl1);
        xA1 = qA; xB1 = qB;
    }
#undef LOADB
#undef MSTEP

    // ---- logit exchange: C layout col=lane&15 (expert-in-group), row=kg*4+reg ----
    #pragma unroll
    for (int g = 0; g < 4; ++g)
        #pragma unroll
        for (int r = 0; r < 4; ++r)
            lg[(wv * 16 + kg * 4 + r) * 68 + g * 16 + row] = acc[g][r];
    __syncthreads();

    // ---- softmax/top2 for tokens wv*16 .. wv*16+15 ; lane = expert ----
    {
        float pacc = 0.0f, facc = 0.0f;
        for (int i = 0; i < 16; ++i) {
            const int tk = wv * 16 + i;
            const float v = lg[tk * 68 + lane];
            float m1 = v; int i1 = lane;
            #pragma unroll
            for (int off = 32; off; off >>= 1) {
                const float ov = __shfl_xor(m1, off, 64);
                const int   oi = __shfl_xor(i1, off, 64);
                if (ov > m1 || (ov == m1 && oi < i1)) { m1 = ov; i1 = oi; }
            }
            const float vx = (lane == i1) ? -3.4e38f : v;
            float m2 = vx; int i2 = lane;
            #pragma unroll
            for (int off = 32; off; off >>= 1) {
                const float ov = __shfl_xor(m2, off, 64);
                const int   oi = __shfl_xor(i2, off, 64);
                if (ov > m2 || (ov == m2 && oi < i2)) { m2 = ov; i2 = oi; }
            }
            const float p = __expf(v - m1);
            float s = p;
            #pragma unroll
            for (int off = 32; off; off >>= 1) s += __shfl_xor(s, off, 64);
            const float rZ = 1.0f / s;
            const float pn = p * rZ;
            const int   T  = tok0b + tk;
            out[65536 + (size_t)T * 64 + lane] = pn;      // coalesced 256 B
            pacc += pn;
            facc += (lane == i1 ? 1.0f : 0.0f) + (lane == i2 ? 1.0f : 0.0f);
            if (lane == 0) {
                const float q1 = rZ, q2 = __expf(m2 - m1) * rZ;
                const float dn = 1.0f / (q1 + q2 + 1e-8f);
                float2 tw; tw.x = q1 * dn; tw.y = q2 * dn;
                *(float2*)(out + (size_t)T * 2) = tw;
                float2 ti; ti.x = (float)i1; ti.y = (float)i2;
                *(float2*)(out + 32768 + (size_t)T * 2) = ti;
            }
        }
        pf[wv * 128 + lane]      = pacc;
        pf[wv * 128 + 64 + lane] = facc;
    }
    __syncthreads();

    // ---- block-level P/f reduce -> one atomic per address per block (8 slots) ----
    if (wv == 0) {
        float ps = 0.0f, fs = 0.0f;
        #pragma unroll
        for (int w2 = 0; w2 < 4; ++w2) {
            ps += pf[w2 * 128 + lane];
            fs += pf[w2 * 128 + 64 + lane];
        }
        const int slot = blockIdx.x & 7;
        atomicAdd(wacc + slot * 128 + lane, ps);
        atomicAdd(wacc + slot * 128 + 64 + lane, fs);
    }
}

// ---------------- kernel 3: aux loss ----------------------------------------------
__global__ void k3_aux(const float* __restrict__ wsb, float* __restrict__ out) {
    const int e = threadIdx.x;  // 64 threads
    float P = 0.0f, F = 0.0f;
    #pragma unroll
    for (int s = 0; s < 8; ++s) {
        P += wsb[256 + s * 128 + e];
        F += wsb[256 + s * 128 + 64 + e];
    }
    float val = P * F;
    #pragma unroll
    for (int off = 32; off; off >>= 1) val += __shfl_xor(val, off, 64);
    if (e == 0)
        out[1114112] = 64.0f * val / (16384.0f * 2.0f * 16384.0f);
}

extern "C" void kernel_launch(void* const* d_in, const int* in_sizes, int n_in,
                              void* d_out, int out_size, void* d_ws, size_t ws_size,
                              hipStream_t stream) {
    (void)in_sizes; (void)n_in; (void)out_size; (void)ws_size;
    const float* x  = (const float*)d_in[0];
    const float* z  = (const float*)d_in[1];
    const float* Wr = (const float*)d_in[2];
    const float* Wp = (const float*)d_in[3];
    const float* bp = (const float*)d_in[4];
    const float* eb = (const float*)d_in[5];
    float* out = (float*)d_out;
    float* wsb = (float*)d_ws;
    u32*   wfH = (u32*)(wsb + 1280);          // 65536 u32 (256 KB)
    u32*   wfL = wfH + 65536;                 // 65536 u32 (256 KB)

    hipLaunchKernelGGL(k0_wsplit, dim3(256), dim3(256), 0, stream, Wr, wfH, wfL);
    hipLaunchKernelGGL(k1_task,   dim3(1),   dim3(256), 0, stream, z, Wp, bp, Wr, eb, wsb);
    hipLaunchKernelGGL(k2_mfma,   dim3(256), dim3(256), 0, stream, x, wsb,
                       (const short8*)wfH, (const short8*)wfL, wsb + 256, out);
    hipLaunchKernelGGL(k3_aux,    dim3(1),   dim3(64),  0, stream, wsb, out);
}